// Round 2
// baseline (1741.158 us; speedup 1.0000x reference)
//
#include <hip/hip_runtime.h>
#include <hip/hip_bf16.h>

// Problem constants
#define NB_  16
#define NPTS 8192
#define NG   256
#define NP   (NB_*NPTS)   // 131072 points

// Output segment offsets (floats)
#define OFF_CENT 0
#define OFF_OUT  12288
#define OFF_PI   1060864
#define OFF_LAB  1454080

// Workspace layout (bytes) — must fit in 256 MiB
static constexpr size_t WS_SUMS  = 0;                               // B*G*4 f32 = 64KB
static constexpr size_t WS_A1    = 65536;                           // P*128 bf16 = 32MB
static constexpr size_t WS_H     = WS_A1   + (size_t)NP*128*2;      // P*256 bf16 = 64MB
static constexpr size_t WS_U     = WS_H    + (size_t)NP*256*2;      // P*512 bf16 = 128MB
static constexpr size_t WS_POOLU = WS_U    + (size_t)NP*512*2;      // B*G*256 u32 = 4MB
static constexpr size_t WS_POOLF = WS_POOLU + (size_t)NB_*NG*256*4; // B*G*256 f32 = 4MB
static constexpr size_t WS_OUTU  = WS_POOLF + (size_t)NB_*NG*256*4; // B*G*256 u32 = 4MB
static constexpr size_t WS_NEED  = WS_OUTU  + (size_t)NB_*NG*256*4; // ~236 MB

// Order-preserving float<->uint mapping for atomicMax-based segment max
__device__ __forceinline__ unsigned mapf(float x){
  unsigned u = __float_as_uint(x);
  return (u & 0x80000000u) ? ~u : (u | 0x80000000u);
}
__device__ __forceinline__ float unmapf(unsigned u){
  return (u & 0x80000000u) ? __uint_as_float(u & 0x7FFFFFFFu) : __uint_as_float(~u);
}
#define MAP_NEG_INF 0x007FFFFFu   // mapf(-inf)

__device__ __forceinline__ unsigned short f2bf_bits(float f){
  __hip_bfloat16 h = __float2bfloat16(f);
  union { __hip_bfloat16 h; unsigned short s; } u; u.h = h; return u.s;
}
__device__ __forceinline__ float bf_bits2f(unsigned short s){
  return __uint_as_float(((unsigned)s) << 16);
}

// ---------------- init: zero sums, -inf the max buffers ----------------
__global__ void k_init(float* __restrict__ sums, unsigned* __restrict__ pool_u,
                       unsigned* __restrict__ out_u){
  int i = blockIdx.x*blockDim.x + threadIdx.x;
  if (i < NB_*NG*4) sums[i] = 0.f;
  if (i < NB_*NG*256){ pool_u[i] = MAP_NEG_INF; out_u[i] = MAP_NEG_INF; }
}

// ---------------- per-point pass 1: segment sums + labels-as-float ----------------
__global__ void k_points(const float* __restrict__ xyz, const int* __restrict__ labels,
                         float* __restrict__ sums, float* __restrict__ outLab){
  int p = blockIdx.x*blockDim.x + threadIdx.x;
  if (p >= NP) return;
  int b = p / NPTS;
  int g = labels[p];
  float x = xyz[p*3+0], y = xyz[p*3+1], z = xyz[p*3+2];
  float* s = sums + (size_t)(b*NG + g)*4;
  atomicAdd(s+0, x); atomicAdd(s+1, y); atomicAdd(s+2, z); atomicAdd(s+3, 1.f);
  outLab[p] = (float)g;
}

// ---------------- centroids ----------------
__global__ void k_cent(const float* __restrict__ sums, float* __restrict__ cent_out){
  int i = blockIdx.x*blockDim.x + threadIdx.x;   // b*G+g
  if (i >= NB_*NG) return;
  const float* s = sums + (size_t)i*4;
  float c = fmaxf(s[3], 1.f);
  cent_out[i*3+0] = s[0]/c;
  cent_out[i*3+1] = s[1]/c;
  cent_out[i*3+2] = s[2]/c;
}

// ---------------- MLP1 front: rel@w1a+b1a -> LN -> ReLU -> a1 (bf16), also p_i ----------------
// one wave per point; lane holds 2 of 128 channels
__global__ __launch_bounds__(256) void k_mlp1(
    const float* __restrict__ xyz, const int* __restrict__ labels,
    const float* __restrict__ cent,
    const float* __restrict__ w1a, const float* __restrict__ b1a,
    const float* __restrict__ g1, const float* __restrict__ beta1,
    __hip_bfloat16* __restrict__ a1, float* __restrict__ pi_out)
{
  int wave = (int)((blockIdx.x*blockDim.x + threadIdx.x) >> 6);
  int lane = threadIdx.x & 63;
  int p = wave;
  if (p >= NP) return;
  int b = p / NPTS;
  int g = labels[p];
  const float* cb = cent + (size_t)(b*NG+g)*3;
  float c0 = cb[0], c1 = cb[1], c2 = cb[2];
  float r0 = xyz[p*3+0]-c0, r1 = xyz[p*3+1]-c1, r2 = xyz[p*3+2]-c2;
  if (lane < 3) pi_out[(size_t)p*3+lane] = (lane==0?c0:(lane==1?c1:c2));
  int j = lane*2;
  float2 wa0 = *(const float2*)(w1a + 0*128 + j);
  float2 wa1 = *(const float2*)(w1a + 1*128 + j);
  float2 wa2 = *(const float2*)(w1a + 2*128 + j);
  float2 bb  = *(const float2*)(b1a + j);
  float t0 = bb.x + r0*wa0.x + r1*wa1.x + r2*wa2.x;
  float t1 = bb.y + r0*wa0.y + r1*wa1.y + r2*wa2.y;
  float s = t0+t1, sq = t0*t0 + t1*t1;
  #pragma unroll
  for (int m = 32; m; m >>= 1){ s += __shfl_xor(s, m); sq += __shfl_xor(sq, m); }
  float mu  = s * (1.f/128.f);
  float var = sq * (1.f/128.f) - mu*mu;
  float inv = rsqrtf(var + 1e-5f);
  float2 gg = *(const float2*)(g1 + j), be = *(const float2*)(beta1 + j);
  float a0 = fmaxf((t0-mu)*inv*gg.x + be.x, 0.f);
  float a1v = fmaxf((t1-mu)*inv*gg.y + be.y, 0.f);
  __hip_bfloat162 pk;
  pk.x = __float2bfloat16(a0);
  pk.y = __float2bfloat16(a1v);
  *reinterpret_cast<__hip_bfloat162*>(a1 + (size_t)p*128 + j) = pk;
}

// ---------------- generic fp32 tiled GEMM, bf16 A (+optional gathered f32 A0), f32 B ----
// C[M][Nc] = A@B + bias.  Col k<splitK from A0, else A1 (both lda).
// GA=1: A0 region is gathered from gsrc (f32 [B*G][256]) via labels (the "rep" matrix).
// EPI 0: store bf16 C + atomicMax pool;  1: store bf16 C;  2: atomicMax only.
template<int EPI, int GA>
__global__ __launch_bounds__(256)
void gemm_k(const __hip_bfloat16* __restrict__ A0,
            const __hip_bfloat16* __restrict__ A1,
            const float* __restrict__ gsrc,
            int lda, int splitK, int K,
            const float* __restrict__ Bw, int ldb, int Nc,
            const float* __restrict__ bias,
            const int* __restrict__ labels,
            __hip_bfloat16* __restrict__ Cst, int ldc,
            unsigned* __restrict__ maxbuf)
{
  __shared__ float As[16][68];   // 68 keeps float4 rows 16B-aligned, spreads banks
  __shared__ float Bs[16][68];
  int NBk = Nc / 64;
  int bm = blockIdx.x / NBk, bn = blockIdx.x % NBk;
  int m0 = bm*64, n0 = bn*64;
  int tid = threadIdx.x;
  int tx = tid & 15, ty = tid >> 4;
  int ar = tid >> 2, ac4 = (tid & 3)*4;     // A staging: 64 rows x 16 k
  int br = tid >> 4, bc4 = (tid & 15)*4;    // B staging: 16 k x 64 n
  const float* grow = nullptr;
  if (GA){
    int m = m0 + ar;
    int b = m / NPTS, g = labels[m];
    grow = gsrc + (size_t)(b*NG + g)*256;
  }
  float acc[4][4] = {};
  for (int k0 = 0; k0 < K; k0 += 16){
    if (GA && k0 < splitK){
      float4 v = *(const float4*)(grow + k0 + ac4);
      As[ac4+0][ar] = v.x;
      As[ac4+1][ar] = v.y;
      As[ac4+2][ar] = v.z;
      As[ac4+3][ar] = v.w;
    } else {
      const __hip_bfloat16* Ap; int kk0;
      if (k0 < splitK){ Ap = A0; kk0 = k0; } else { Ap = A1; kk0 = k0 - splitK; }
      ushort4 av = *(const ushort4*)(Ap + (size_t)(m0+ar)*lda + kk0 + ac4);
      As[ac4+0][ar] = bf_bits2f(av.x);
      As[ac4+1][ar] = bf_bits2f(av.y);
      As[ac4+2][ar] = bf_bits2f(av.z);
      As[ac4+3][ar] = bf_bits2f(av.w);
    }
    float4 bvv = *(const float4*)(Bw + (size_t)(k0+br)*ldb + n0 + bc4);
    *(float4*)&Bs[br][bc4] = bvv;
    __syncthreads();
    #pragma unroll
    for (int kk = 0; kk < 16; ++kk){
      float avr[4], bvr[4];
      *(float4*)avr = *(const float4*)&As[kk][ty*4];
      *(float4*)bvr = *(const float4*)&Bs[kk][tx*4];
      #pragma unroll
      for (int i = 0; i < 4; ++i)
        #pragma unroll
        for (int jj = 0; jj < 4; ++jj)
          acc[i][jj] = fmaf(avr[i], bvr[jj], acc[i][jj]);
    }
    __syncthreads();
  }
  // epilogue
  #pragma unroll
  for (int i = 0; i < 4; ++i){
    int m = m0 + ty*4 + i;
    int b = 0, g = 0;
    if (EPI == 0 || EPI == 2){ g = labels[m]; b = m / NPTS; }
    float v[4];
    #pragma unroll
    for (int jj = 0; jj < 4; ++jj){
      int n = n0 + tx*4 + jj;
      v[jj] = acc[i][jj] + bias[n];
    }
    if (EPI <= 1){
      ushort4 st;
      st.x = f2bf_bits(v[0]); st.y = f2bf_bits(v[1]);
      st.z = f2bf_bits(v[2]); st.w = f2bf_bits(v[3]);
      *(ushort4*)(Cst + (size_t)m*ldc + n0 + tx*4) = st;
    }
    if (EPI == 0 || EPI == 2){
      unsigned* mb = maxbuf + ((size_t)(b*NG+g)*256 + n0 + tx*4);
      #pragma unroll
      for (int jj = 0; jj < 4; ++jj)
        atomicMax(mb + jj, mapf(v[jj]));
    }
  }
}

// ---------------- pooled finalize: unmap, -inf -> 0, to f32 ----------------
__global__ void k_poolfin(const unsigned* __restrict__ pu, float* __restrict__ pf){
  int i = blockIdx.x*blockDim.x + threadIdx.x;
  if (i >= NB_*NG*256) return;
  float v = unmapf(pu[i]);
  pf[i] = (v > -3.0e38f) ? v : 0.f;
}

// ---------------- LN2+ReLU in-place on u [P][512] bf16; wave per row ----------------
__global__ __launch_bounds__(256) void k_ln2(__hip_bfloat16* __restrict__ u,
                                             const float* __restrict__ g2,
                                             const float* __restrict__ beta2){
  int row = (int)((blockIdx.x*blockDim.x + threadIdx.x) >> 6);
  int lane = threadIdx.x & 63;
  if (row >= NP) return;
  __hip_bfloat16* r = u + (size_t)row*512;
  int c0 = lane*8;
  ushort4 lo = *(const ushort4*)(r + c0);
  ushort4 hi = *(const ushort4*)(r + c0 + 4);
  float v[8];
  v[0]=bf_bits2f(lo.x); v[1]=bf_bits2f(lo.y); v[2]=bf_bits2f(lo.z); v[3]=bf_bits2f(lo.w);
  v[4]=bf_bits2f(hi.x); v[5]=bf_bits2f(hi.y); v[6]=bf_bits2f(hi.z); v[7]=bf_bits2f(hi.w);
  float s = 0.f, sq = 0.f;
  #pragma unroll
  for (int k = 0; k < 8; ++k){ s += v[k]; sq += v[k]*v[k]; }
  #pragma unroll
  for (int m = 32; m; m >>= 1){ s += __shfl_xor(s, m); sq += __shfl_xor(sq, m); }
  float mu  = s * (1.f/512.f);
  float var = sq * (1.f/512.f) - mu*mu;
  float inv = rsqrtf(var + 1e-5f);
  float4 gA = *(const float4*)(g2 + c0), gB = *(const float4*)(g2 + c0 + 4);
  float4 bA = *(const float4*)(beta2 + c0), bB = *(const float4*)(beta2 + c0 + 4);
  float gg[8] = {gA.x,gA.y,gA.z,gA.w,gB.x,gB.y,gB.z,gB.w};
  float bb[8] = {bA.x,bA.y,bA.z,bA.w,bB.x,bB.y,bB.z,bB.w};
  ushort4 so, so2;
  unsigned short o[8];
  #pragma unroll
  for (int k = 0; k < 8; ++k)
    o[k] = f2bf_bits(fmaxf((v[k]-mu)*inv*gg[k] + bb[k], 0.f));
  so.x=o[0]; so.y=o[1]; so.z=o[2]; so.w=o[3];
  so2.x=o[4]; so2.y=o[5]; so2.z=o[6]; so2.w=o[7];
  *(ushort4*)(r + c0) = so;
  *(ushort4*)(r + c0 + 4) = so2;
}

// ---------------- out finalize ----------------
__global__ void k_outfin(const unsigned* __restrict__ ou, float* __restrict__ dst){
  int i = blockIdx.x*blockDim.x + threadIdx.x;
  if (i >= NB_*NG*256) return;
  float v = unmapf(ou[i]);
  dst[i] = (v > -3.0e38f) ? v : 0.f;
}

// ---------------- ws-too-small signal ----------------
__global__ void k_sig(float* __restrict__ out, float val){
  int i = blockIdx.x*blockDim.x + threadIdx.x;
  if (i < 256) out[i] = val;
}

extern "C" void kernel_launch(void* const* d_in, const int* in_sizes, int n_in,
                              void* d_out, int out_size, void* d_ws, size_t ws_size,
                              hipStream_t stream) {
  const float* xyz    = (const float*)d_in[0];
  const int*   labels = (const int*)  d_in[1];
  const float* w1a    = (const float*)d_in[2];
  const float* b1a    = (const float*)d_in[3];
  const float* g1     = (const float*)d_in[4];
  const float* beta1  = (const float*)d_in[5];
  const float* w1b    = (const float*)d_in[6];
  const float* b1b    = (const float*)d_in[7];
  const float* w2a    = (const float*)d_in[8];
  const float* b2a    = (const float*)d_in[9];
  const float* g2     = (const float*)d_in[10];
  const float* beta2  = (const float*)d_in[11];
  const float* w2b    = (const float*)d_in[12];
  const float* b2b    = (const float*)d_in[13];
  float* out = (float*)d_out;
  char* ws = (char*)d_ws;

  if (ws_size < WS_NEED){
    // signal actual ws size (MB) through output 0's absmax error
    k_sig<<<1, 256, 0, stream>>>(out, 10000.f + (float)(ws_size >> 20));
    return;
  }

  float*           sums   = (float*)(ws + WS_SUMS);
  __hip_bfloat16*  a1     = (__hip_bfloat16*)(ws + WS_A1);
  __hip_bfloat16*  h      = (__hip_bfloat16*)(ws + WS_H);
  __hip_bfloat16*  u      = (__hip_bfloat16*)(ws + WS_U);
  unsigned*        pool_u = (unsigned*)(ws + WS_POOLU);
  float*           poolf  = (float*)(ws + WS_POOLF);
  unsigned*        out_u  = (unsigned*)(ws + WS_OUTU);

  float* cent_out = out + OFF_CENT;
  float* out_seg  = out + OFF_OUT;
  float* pi_out   = out + OFF_PI;
  float* lab_out  = out + OFF_LAB;

  k_init<<<4096, 256, 0, stream>>>(sums, pool_u, out_u);
  k_points<<<NP/256, 256, 0, stream>>>(xyz, labels, sums, lab_out);
  k_cent<<<(NB_*NG+255)/256, 256, 0, stream>>>(sums, cent_out);
  k_mlp1<<<NP/4, 256, 0, stream>>>(xyz, labels, cent_out, w1a, b1a, g1, beta1, a1, pi_out);
  // GEMM1: h = a1 @ w1b + b1b ; store bf16 + pool max
  gemm_k<0,0><<<(NP/64)*(256/64), 256, 0, stream>>>(a1, a1, (const float*)nullptr,
      128, 128, 128, w1b, 256, 256, b1b, labels, h, 256, pool_u);
  k_poolfin<<<4096, 256, 0, stream>>>(pool_u, poolf);
  // GEMM2a: u = [rep|h] @ w2a + b2a ; rep gathered from poolf on the fly
  gemm_k<1,1><<<(NP/64)*(512/64), 256, 0, stream>>>((const __hip_bfloat16*)nullptr, h, poolf,
      256, 256, 512, w2a, 512, 512, b2a, labels, u, 512, (unsigned*)nullptr);
  k_ln2<<<NP/4, 256, 0, stream>>>(u, g2, beta2);
  // GEMM2b: v = u @ w2b + b2b ; atomicMax into out_u
  gemm_k<2,0><<<(NP/64)*(256/64), 256, 0, stream>>>(u, u, (const float*)nullptr,
      512, 512, 512, w2b, 256, 256, b2b, labels, (__hip_bfloat16*)nullptr, 0, out_u);
  k_outfin<<<4096, 256, 0, stream>>>(out_u, out_seg);
}

// Round 3
// 431.562 us; speedup vs baseline: 4.0345x; 4.0345x over previous
//
#include <hip/hip_runtime.h>
#include <hip/hip_bf16.h>

// Problem constants
#define NB_  16
#define NPTS 8192
#define NG   256
#define NP   (NB_*NPTS)   // 131072 points

// Output segment offsets (floats)
#define OFF_CENT 0
#define OFF_OUT  12288
#define OFF_PI   1060864
#define OFF_LAB  1454080

typedef unsigned short u16;
typedef __attribute__((ext_vector_type(8))) short bf16x8;
typedef __attribute__((ext_vector_type(4))) float f32x4;

// Workspace layout (bytes) — must fit in 256 MiB
static constexpr size_t WS_SUMS  = 0;                                // B*G*4 f32 = 64KB
static constexpr size_t WS_A1    = 65536;                            // P*128 bf16 = 32MB
static constexpr size_t WS_H     = WS_A1   + (size_t)NP*128*2;       // P*256 bf16 = 64MB
static constexpr size_t WS_U     = WS_H    + (size_t)NP*256*2;       // P*512 bf16 = 128MB
static constexpr size_t WS_POOLU = WS_U    + (size_t)NP*512*2;       // B*G*256 u32 = 4MB
static constexpr size_t WS_PBF   = WS_POOLU + (size_t)NB_*NG*256*4;  // B*G*256 bf16 = 2MB
static constexpr size_t WS_OUTU  = WS_PBF   + (size_t)NB_*NG*256*2;  // B*G*256 u32 = 4MB
static constexpr size_t WS_WT1   = WS_OUTU  + (size_t)NB_*NG*256*4;  // 256x128 bf16 = 64KB
static constexpr size_t WS_WT2A  = WS_WT1   + (size_t)256*128*2;     // 512x512 bf16 = 512KB
static constexpr size_t WS_WT2B  = WS_WT2A  + (size_t)512*512*2;     // 256x512 bf16 = 256KB
static constexpr size_t WS_NEED  = WS_WT2B  + (size_t)256*512*2;     // ~235 MB

// Order-preserving float<->uint mapping for atomicMax-based segment max
__device__ __forceinline__ unsigned mapf(float x){
  unsigned u = __float_as_uint(x);
  return (u & 0x80000000u) ? ~u : (u | 0x80000000u);
}
__device__ __forceinline__ float unmapf(unsigned u){
  return (u & 0x80000000u) ? __uint_as_float(u & 0x7FFFFFFFu) : __uint_as_float(~u);
}
#define MAP_NEG_INF 0x007FFFFFu   // mapf(-inf)

__device__ __forceinline__ u16 f2bf_bits(float f){
  __hip_bfloat16 h = __float2bfloat16(f);
  union { __hip_bfloat16 h; u16 s; } u; u.h = h; return u.s;
}
__device__ __forceinline__ float bf_bits2f(u16 s){
  return __uint_as_float(((unsigned)s) << 16);
}

// async global->LDS, 16B per lane. LDS dest must be wave-uniform base (lane*16 added by HW).
__device__ __forceinline__ void gload16(const void* g, void* l){
  __builtin_amdgcn_global_load_lds((const __attribute__((address_space(1))) void*)g,
                                   (__attribute__((address_space(3))) void*)l, 16, 0, 0);
}

// ---------------- init: zero sums, -inf the max buffers ----------------
__global__ void k_init(float* __restrict__ sums, unsigned* __restrict__ pool_u,
                       unsigned* __restrict__ out_u){
  int i = blockIdx.x*blockDim.x + threadIdx.x;
  if (i < NB_*NG*4) sums[i] = 0.f;
  if (i < NB_*NG*256){ pool_u[i] = MAP_NEG_INF; out_u[i] = MAP_NEG_INF; }
}

// ---------------- weight transpose+bf16: dst[n*K+k] = bf16(src[k*N+n]) ----------------
__global__ void k_wt(const float* __restrict__ src, u16* __restrict__ dst, int K, int N){
  int i = blockIdx.x*blockDim.x + threadIdx.x;
  if (i >= K*N) return;
  int n = i / K, k = i - n*K;
  dst[i] = f2bf_bits(src[(size_t)k*N + n]);
}

// ---------------- per-point pass 1: segment sums + labels-as-float ----------------
__global__ void k_points(const float* __restrict__ xyz, const int* __restrict__ labels,
                         float* __restrict__ sums, float* __restrict__ outLab){
  int p = blockIdx.x*blockDim.x + threadIdx.x;
  if (p >= NP) return;
  int b = p / NPTS;
  int g = labels[p];
  float x = xyz[p*3+0], y = xyz[p*3+1], z = xyz[p*3+2];
  float* s = sums + (size_t)(b*NG + g)*4;
  atomicAdd(s+0, x); atomicAdd(s+1, y); atomicAdd(s+2, z); atomicAdd(s+3, 1.f);
  outLab[p] = (float)g;
}

// ---------------- centroids ----------------
__global__ void k_cent(const float* __restrict__ sums, float* __restrict__ cent_out){
  int i = blockIdx.x*blockDim.x + threadIdx.x;   // b*G+g
  if (i >= NB_*NG) return;
  const float* s = sums + (size_t)i*4;
  float c = fmaxf(s[3], 1.f);
  cent_out[i*3+0] = s[0]/c;
  cent_out[i*3+1] = s[1]/c;
  cent_out[i*3+2] = s[2]/c;
}

// ---------------- MLP1 front: rel@w1a+b1a -> LN -> ReLU -> a1 (bf16), also p_i ----------------
__global__ __launch_bounds__(256) void k_mlp1(
    const float* __restrict__ xyz, const int* __restrict__ labels,
    const float* __restrict__ cent,
    const float* __restrict__ w1a, const float* __restrict__ b1a,
    const float* __restrict__ g1, const float* __restrict__ beta1,
    u16* __restrict__ a1, float* __restrict__ pi_out)
{
  int wave = (int)((blockIdx.x*blockDim.x + threadIdx.x) >> 6);
  int lane = threadIdx.x & 63;
  int p = wave;
  if (p >= NP) return;
  int b = p / NPTS;
  int g = labels[p];
  const float* cb = cent + (size_t)(b*NG+g)*3;
  float c0 = cb[0], c1 = cb[1], c2 = cb[2];
  float r0 = xyz[p*3+0]-c0, r1 = xyz[p*3+1]-c1, r2 = xyz[p*3+2]-c2;
  if (lane < 3) pi_out[(size_t)p*3+lane] = (lane==0?c0:(lane==1?c1:c2));
  int j = lane*2;
  float2 wa0 = *(const float2*)(w1a + 0*128 + j);
  float2 wa1 = *(const float2*)(w1a + 1*128 + j);
  float2 wa2 = *(const float2*)(w1a + 2*128 + j);
  float2 bb  = *(const float2*)(b1a + j);
  float t0 = bb.x + r0*wa0.x + r1*wa1.x + r2*wa2.x;
  float t1 = bb.y + r0*wa0.y + r1*wa1.y + r2*wa2.y;
  float s = t0+t1, sq = t0*t0 + t1*t1;
  #pragma unroll
  for (int m = 32; m; m >>= 1){ s += __shfl_xor(s, m); sq += __shfl_xor(sq, m); }
  float mu  = s * (1.f/128.f);
  float var = sq * (1.f/128.f) - mu*mu;
  float inv = rsqrtf(var + 1e-5f);
  float2 gg = *(const float2*)(g1 + j), be = *(const float2*)(beta1 + j);
  float a0 = fmaxf((t0-mu)*inv*gg.x + be.x, 0.f);
  float a1v = fmaxf((t1-mu)*inv*gg.y + be.y, 0.f);
  unsigned pk = ((unsigned)f2bf_bits(a1v) << 16) | f2bf_bits(a0);
  *reinterpret_cast<unsigned*>(a1 + (size_t)p*128 + j) = pk;
}

// ---------------- MFMA bf16 GEMM: C[M][Nc] = A@B + bias ----------------
// A row-major bf16 [M][lda].  B passed TRANSPOSED bf16: BT[Nc][K].
// GA=1: cols k<splitK gathered per-row from gsrc[(b*G+labels[m])*256 + k]; cols >= splitK from A1
//       (lda applies to A1, k offset k-splitK).
// EPI 0: store bf16 C + atomicMax pool;  1: store bf16 C;  2: atomicMax only.
// 128x128 tile, BK=32, 256 threads (4 waves, each one 64x64 quadrant of 4x4 16x16 frags).
template<int EPI, int GA>
__global__ __launch_bounds__(256)
void mgemm(const u16* __restrict__ A1, const u16* __restrict__ gsrc,
           int lda, int splitK, int K,
           const u16* __restrict__ BT,
           const float* __restrict__ bias,
           const int* __restrict__ labels,
           u16* __restrict__ Cst, int ldc, int Nc,
           unsigned* __restrict__ maxbuf)
{
  __shared__ alignas(16) u16 As[128*32];
  __shared__ alignas(16) u16 Bs[128*32];
  int NBk = Nc >> 7;
  int bm = blockIdx.x / NBk, bn = blockIdx.x % NBk;
  int m0 = bm << 7, n0 = bn << 7;
  int tid = threadIdx.x;
  int lane = tid & 63, w = tid >> 6;
  int wr = w >> 1, wc = w & 1;
  int l15 = lane & 15, l4 = lane >> 4;
  // staging geometry: instr j in {0,1}: idx = j*256 + tid; row = idx>>2, kseg = (idx&3)*8
  int r0 = tid >> 2;             // row for j=0 (j=1 adds 64)
  int ks = (tid & 3) << 3;       // k element offset within tile
  // wave-uniform LDS dest bases (16B per lane appended by HW)
  u16* asd0 = As + (size_t)(w*64)*8;
  u16* asd1 = As + (size_t)(256 + w*64)*8;
  u16* bsd0 = Bs + (size_t)(w*64)*8;
  u16* bsd1 = Bs + (size_t)(256 + w*64)*8;
  // gather row bases
  const u16* grow0 = nullptr; const u16* grow1 = nullptr;
  if (GA){
    int mA = m0 + r0;
    int mB = mA + 64;
    grow0 = gsrc + (((size_t)(mA/NPTS)*NG + labels[mA]) << 8);
    grow1 = gsrc + (((size_t)(mB/NPTS)*NG + labels[mB]) << 8);
  }
  f32x4 acc[4][4];
  #pragma unroll
  for (int i = 0; i < 4; ++i)
    #pragma unroll
    for (int jj = 0; jj < 4; ++jj)
      #pragma unroll
      for (int e = 0; e < 4; ++e) acc[i][jj][e] = 0.f;

  for (int k0 = 0; k0 < K; k0 += 32){
    // stage A tile [128][32]
    if (GA && k0 < splitK){
      gload16(grow0 + k0 + ks, asd0);
      gload16(grow1 + k0 + ks, asd1);
    } else {
      int kk = GA ? (k0 - splitK) : k0;
      gload16(A1 + (size_t)(m0 + r0)*lda + kk + ks, asd0);
      gload16(A1 + (size_t)(m0 + r0 + 64)*lda + kk + ks, asd1);
    }
    // stage B^T tile [128][32]
    gload16(BT + (size_t)(n0 + r0)*K + k0 + ks, bsd0);
    gload16(BT + (size_t)(n0 + r0 + 64)*K + k0 + ks, bsd1);
    __syncthreads();   // drains vmcnt(0): tiles complete
    bf16x8 af[4], bfr[4];
    #pragma unroll
    for (int i = 0; i < 4; ++i){
      af[i]  = *(const bf16x8*)&As[(size_t)(wr*64 + i*16 + l15)*32 + l4*8];
      bfr[i] = *(const bf16x8*)&Bs[(size_t)(wc*64 + i*16 + l15)*32 + l4*8];
    }
    #pragma unroll
    for (int i = 0; i < 4; ++i)
      #pragma unroll
      for (int jj = 0; jj < 4; ++jj)
        acc[i][jj] = __builtin_amdgcn_mfma_f32_16x16x32_bf16(af[i], bfr[jj], acc[i][jj], 0, 0, 0);
    __syncthreads();   // all reads done before next stage
  }

  // epilogue: D element (lane,reg): row = m0+wr*64+i*16+4*l4+reg, col = n0+wc*64+jj*16+l15
  float bi[4];
  #pragma unroll
  for (int jj = 0; jj < 4; ++jj) bi[jj] = bias[n0 + wc*64 + jj*16 + l15];
  #pragma unroll
  for (int i = 0; i < 4; ++i){
    #pragma unroll
    for (int r = 0; r < 4; ++r){
      int m = m0 + wr*64 + i*16 + l4*4 + r;
      size_t mgb = 0;
      if (EPI != 1) mgb = (((size_t)(m/NPTS)*NG + labels[m]) << 8);
      #pragma unroll
      for (int jj = 0; jj < 4; ++jj){
        int n = n0 + wc*64 + jj*16 + l15;
        float v = acc[i][jj][r] + bi[jj];
        if (EPI <= 1) Cst[(size_t)m*ldc + n] = f2bf_bits(v);
        if (EPI != 1) atomicMax(maxbuf + mgb + n, mapf(v));
      }
    }
  }
}

// ---------------- pooled finalize: unmap, -inf -> 0, to bf16 ----------------
__global__ void k_poolfin(const unsigned* __restrict__ pu, u16* __restrict__ pbf){
  int i = blockIdx.x*blockDim.x + threadIdx.x;
  if (i >= NB_*NG*256) return;
  float v = unmapf(pu[i]);
  pbf[i] = f2bf_bits((v > -3.0e38f) ? v : 0.f);
}

// ---------------- LN2+ReLU in-place on u [P][512] bf16; wave per row ----------------
__global__ __launch_bounds__(256) void k_ln2(u16* __restrict__ u,
                                             const float* __restrict__ g2,
                                             const float* __restrict__ beta2){
  int row = (int)((blockIdx.x*blockDim.x + threadIdx.x) >> 6);
  int lane = threadIdx.x & 63;
  if (row >= NP) return;
  u16* r = u + (size_t)row*512;
  int c0 = lane*8;
  ushort4 lo = *(const ushort4*)(r + c0);
  ushort4 hi = *(const ushort4*)(r + c0 + 4);
  float v[8];
  v[0]=bf_bits2f(lo.x); v[1]=bf_bits2f(lo.y); v[2]=bf_bits2f(lo.z); v[3]=bf_bits2f(lo.w);
  v[4]=bf_bits2f(hi.x); v[5]=bf_bits2f(hi.y); v[6]=bf_bits2f(hi.z); v[7]=bf_bits2f(hi.w);
  float s = 0.f, sq = 0.f;
  #pragma unroll
  for (int k = 0; k < 8; ++k){ s += v[k]; sq += v[k]*v[k]; }
  #pragma unroll
  for (int m = 32; m; m >>= 1){ s += __shfl_xor(s, m); sq += __shfl_xor(sq, m); }
  float mu  = s * (1.f/512.f);
  float var = sq * (1.f/512.f) - mu*mu;
  float inv = rsqrtf(var + 1e-5f);
  float4 gA = *(const float4*)(g2 + c0), gB = *(const float4*)(g2 + c0 + 4);
  float4 bA = *(const float4*)(beta2 + c0), bB = *(const float4*)(beta2 + c0 + 4);
  float gg[8] = {gA.x,gA.y,gA.z,gA.w,gB.x,gB.y,gB.z,gB.w};
  float bb[8] = {bA.x,bA.y,bA.z,bA.w,bB.x,bB.y,bB.z,bB.w};
  ushort4 so, so2;
  u16 o[8];
  #pragma unroll
  for (int k = 0; k < 8; ++k)
    o[k] = f2bf_bits(fmaxf((v[k]-mu)*inv*gg[k] + bb[k], 0.f));
  so.x=o[0]; so.y=o[1]; so.z=o[2]; so.w=o[3];
  so2.x=o[4]; so2.y=o[5]; so2.z=o[6]; so2.w=o[7];
  *(ushort4*)(r + c0) = so;
  *(ushort4*)(r + c0 + 4) = so2;
}

// ---------------- out finalize ----------------
__global__ void k_outfin(const unsigned* __restrict__ ou, float* __restrict__ dst){
  int i = blockIdx.x*blockDim.x + threadIdx.x;
  if (i >= NB_*NG*256) return;
  float v = unmapf(ou[i]);
  dst[i] = (v > -3.0e38f) ? v : 0.f;
}

// ---------------- ws-too-small signal ----------------
__global__ void k_sig(float* __restrict__ out, float val){
  int i = blockIdx.x*blockDim.x + threadIdx.x;
  if (i < 256) out[i] = val;
}

extern "C" void kernel_launch(void* const* d_in, const int* in_sizes, int n_in,
                              void* d_out, int out_size, void* d_ws, size_t ws_size,
                              hipStream_t stream) {
  const float* xyz    = (const float*)d_in[0];
  const int*   labels = (const int*)  d_in[1];
  const float* w1a    = (const float*)d_in[2];
  const float* b1a    = (const float*)d_in[3];
  const float* g1     = (const float*)d_in[4];
  const float* beta1  = (const float*)d_in[5];
  const float* w1b    = (const float*)d_in[6];
  const float* b1b    = (const float*)d_in[7];
  const float* w2a    = (const float*)d_in[8];
  const float* b2a    = (const float*)d_in[9];
  const float* g2     = (const float*)d_in[10];
  const float* beta2  = (const float*)d_in[11];
  const float* w2b    = (const float*)d_in[12];
  const float* b2b    = (const float*)d_in[13];
  float* out = (float*)d_out;
  char* ws = (char*)d_ws;

  if (ws_size < WS_NEED){
    k_sig<<<1, 256, 0, stream>>>(out, 10000.f + (float)(ws_size >> 20));
    return;
  }

  float*     sums   = (float*)(ws + WS_SUMS);
  u16*       a1     = (u16*)(ws + WS_A1);
  u16*       h      = (u16*)(ws + WS_H);
  u16*       u      = (u16*)(ws + WS_U);
  unsigned*  pool_u = (unsigned*)(ws + WS_POOLU);
  u16*       poolbf = (u16*)(ws + WS_PBF);
  unsigned*  out_u  = (unsigned*)(ws + WS_OUTU);
  u16*       wt1    = (u16*)(ws + WS_WT1);
  u16*       wt2a   = (u16*)(ws + WS_WT2A);
  u16*       wt2b   = (u16*)(ws + WS_WT2B);

  float* cent_out = out + OFF_CENT;
  float* out_seg  = out + OFF_OUT;
  float* pi_out   = out + OFF_PI;
  float* lab_out  = out + OFF_LAB;

  k_init<<<4096, 256, 0, stream>>>(sums, pool_u, out_u);
  // weight conversions (tiny)
  k_wt<<<(128*256+255)/256, 256, 0, stream>>>(w1b, wt1, 128, 256);
  k_wt<<<(512*512+255)/256, 256, 0, stream>>>(w2a, wt2a, 512, 512);
  k_wt<<<(512*256+255)/256, 256, 0, stream>>>(w2b, wt2b, 512, 256);
  k_points<<<NP/256, 256, 0, stream>>>(xyz, labels, sums, lab_out);
  k_cent<<<(NB_*NG+255)/256, 256, 0, stream>>>(sums, cent_out);
  k_mlp1<<<NP/4, 256, 0, stream>>>(xyz, labels, cent_out, w1a, b1a, g1, beta1, a1, pi_out);
  // GEMM1: h = a1 @ w1b + b1b ; store bf16 + pool atomicMax.  M=NP,K=128,N=256
  mgemm<0,0><<<(NP/128)*(256/128), 256, 0, stream>>>(
      a1, (const u16*)nullptr, 128, 0, 128, wt1, b1b, labels, h, 256, 256, pool_u);
  k_poolfin<<<4096, 256, 0, stream>>>(pool_u, poolbf);
  // GEMM2a: u = [rep|h] @ w2a + b2a ; rep gathered from poolbf.  M=NP,K=512,N=512
  mgemm<1,1><<<(NP/128)*(512/128), 256, 0, stream>>>(
      h, poolbf, 256, 256, 512, wt2a, b2a, labels, u, 512, 512, (unsigned*)nullptr);
  k_ln2<<<NP/4, 256, 0, stream>>>(u, g2, beta2);
  // GEMM2b: v = u @ w2b + b2b ; atomicMax only.  M=NP,K=512,N=256
  mgemm<2,0><<<(NP/128)*(256/128), 256, 0, stream>>>(
      u, (const u16*)nullptr, 512, 0, 512, wt2b, b2b, labels, (u16*)nullptr, 0, 256, out_u);
  k_outfin<<<4096, 256, 0, stream>>>(out_u, out_seg);
}

// Round 4
// 431.499 us; speedup vs baseline: 4.0351x; 1.0001x over previous
//
#include <hip/hip_runtime.h>
#include <hip/hip_bf16.h>

// Problem constants
#define NB_  16
#define NPTS 8192
#define NG   256
#define NP   (NB_*NPTS)   // 131072 points

// Output segment offsets (floats)
#define OFF_CENT 0
#define OFF_OUT  12288
#define OFF_PI   1060864
#define OFF_LAB  1454080

typedef unsigned short u16;
typedef __attribute__((ext_vector_type(8))) short bf16x8;
typedef __attribute__((ext_vector_type(4))) float f32x4;

// Workspace layout (bytes) — must fit in 256 MiB
static constexpr size_t WS_SUMS  = 0;                                // B*G*4 f32 = 64KB
static constexpr size_t WS_A1    = 65536;                            // P*128 bf16 = 32MB
static constexpr size_t WS_H     = WS_A1   + (size_t)NP*128*2;       // P*256 bf16 = 64MB
static constexpr size_t WS_U     = WS_H    + (size_t)NP*256*2;       // P*512 bf16 = 128MB
static constexpr size_t WS_POOLU = WS_U    + (size_t)NP*512*2;       // B*G*256 u32 = 4MB
static constexpr size_t WS_PBF   = WS_POOLU + (size_t)NB_*NG*256*4;  // B*G*256 bf16 = 2MB
static constexpr size_t WS_OUTU  = WS_PBF   + (size_t)NB_*NG*256*2;  // B*G*256 u32 = 4MB
static constexpr size_t WS_WT1   = WS_OUTU  + (size_t)NB_*NG*256*4;  // 256x128 bf16 = 64KB
static constexpr size_t WS_WT2A  = WS_WT1   + (size_t)256*128*2;     // 512x512 bf16 = 512KB
static constexpr size_t WS_WT2B  = WS_WT2A  + (size_t)512*512*2;     // 256x512 bf16 = 256KB
static constexpr size_t WS_PREP  = WS_WT2B  + (size_t)256*512*2;     // 4096x512 f32 = 8MB
static constexpr size_t WS_NEED  = WS_PREP  + (size_t)NB_*NG*512*4;  // ~243 MB

// Order-preserving float<->uint mapping for atomicMax-based segment max
__device__ __forceinline__ unsigned mapf(float x){
  unsigned u = __float_as_uint(x);
  return (u & 0x80000000u) ? ~u : (u | 0x80000000u);
}
__device__ __forceinline__ float unmapf(unsigned u){
  return (u & 0x80000000u) ? __uint_as_float(u & 0x7FFFFFFFu) : __uint_as_float(~u);
}
#define MAP_NEG_INF 0x007FFFFFu   // mapf(-inf)

__device__ __forceinline__ u16 f2bf_bits(float f){
  __hip_bfloat16 h = __float2bfloat16(f);
  union { __hip_bfloat16 h; u16 s; } u; u.h = h; return u.s;
}
__device__ __forceinline__ float bf_bits2f(u16 s){
  return __uint_as_float(((unsigned)s) << 16);
}

// async global->LDS, 16B per lane. LDS dest must be wave-uniform base (lane*16 added by HW).
__device__ __forceinline__ void gload16(const void* g, void* l){
  __builtin_amdgcn_global_load_lds((const __attribute__((address_space(1))) void*)g,
                                   (__attribute__((address_space(3))) void*)l, 16, 0, 0);
}

// ---------------- init: zero sums, -inf the max buffers ----------------
__global__ void k_init(float* __restrict__ sums, unsigned* __restrict__ pool_u,
                       unsigned* __restrict__ out_u){
  int i = blockIdx.x*blockDim.x + threadIdx.x;
  if (i < NB_*NG*4) sums[i] = 0.f;
  if (i < NB_*NG*256){ pool_u[i] = MAP_NEG_INF; out_u[i] = MAP_NEG_INF; }
}

// ---------------- weight transpose+bf16: dst[n*K+k] = bf16(src[k*N+n]) ----------------
__global__ void k_wt(const float* __restrict__ src, u16* __restrict__ dst, int K, int N){
  int i = blockIdx.x*blockDim.x + threadIdx.x;
  if (i >= K*N) return;
  int n = i / K, k = i - n*K;
  dst[i] = f2bf_bits(src[(size_t)k*N + n]);
}

// ---------------- per-point pass 1: segment sums + labels-as-float ----------------
__global__ void k_points(const float* __restrict__ xyz, const int* __restrict__ labels,
                         float* __restrict__ sums, float* __restrict__ outLab){
  int p = blockIdx.x*blockDim.x + threadIdx.x;
  if (p >= NP) return;
  int b = p / NPTS;
  int g = labels[p];
  float x = xyz[p*3+0], y = xyz[p*3+1], z = xyz[p*3+2];
  float* s = sums + (size_t)(b*NG + g)*4;
  atomicAdd(s+0, x); atomicAdd(s+1, y); atomicAdd(s+2, z); atomicAdd(s+3, 1.f);
  outLab[p] = (float)g;
}

// ---------------- centroids ----------------
__global__ void k_cent(const float* __restrict__ sums, float* __restrict__ cent_out){
  int i = blockIdx.x*blockDim.x + threadIdx.x;   // b*G+g
  if (i >= NB_*NG) return;
  const float* s = sums + (size_t)i*4;
  float c = fmaxf(s[3], 1.f);
  cent_out[i*3+0] = s[0]/c;
  cent_out[i*3+1] = s[1]/c;
  cent_out[i*3+2] = s[2]/c;
}

// ---------------- MLP1 front: rel@w1a+b1a -> LN -> ReLU -> a1 (bf16), also p_i ----------------
__global__ __launch_bounds__(256) void k_mlp1(
    const float* __restrict__ xyz, const int* __restrict__ labels,
    const float* __restrict__ cent,
    const float* __restrict__ w1a, const float* __restrict__ b1a,
    const float* __restrict__ g1, const float* __restrict__ beta1,
    u16* __restrict__ a1, float* __restrict__ pi_out)
{
  int wave = (int)((blockIdx.x*blockDim.x + threadIdx.x) >> 6);
  int lane = threadIdx.x & 63;
  int p = wave;
  if (p >= NP) return;
  int b = p / NPTS;
  int g = labels[p];
  const float* cb = cent + (size_t)(b*NG+g)*3;
  float c0 = cb[0], c1 = cb[1], c2 = cb[2];
  float r0 = xyz[p*3+0]-c0, r1 = xyz[p*3+1]-c1, r2 = xyz[p*3+2]-c2;
  if (lane < 3) pi_out[(size_t)p*3+lane] = (lane==0?c0:(lane==1?c1:c2));
  int j = lane*2;
  float2 wa0 = *(const float2*)(w1a + 0*128 + j);
  float2 wa1 = *(const float2*)(w1a + 1*128 + j);
  float2 wa2 = *(const float2*)(w1a + 2*128 + j);
  float2 bb  = *(const float2*)(b1a + j);
  float t0 = bb.x + r0*wa0.x + r1*wa1.x + r2*wa2.x;
  float t1 = bb.y + r0*wa0.y + r1*wa1.y + r2*wa2.y;
  float s = t0+t1, sq = t0*t0 + t1*t1;
  #pragma unroll
  for (int m = 32; m; m >>= 1){ s += __shfl_xor(s, m); sq += __shfl_xor(sq, m); }
  float mu  = s * (1.f/128.f);
  float var = sq * (1.f/128.f) - mu*mu;
  float inv = rsqrtf(var + 1e-5f);
  float2 gg = *(const float2*)(g1 + j), be = *(const float2*)(beta1 + j);
  float a0 = fmaxf((t0-mu)*inv*gg.x + be.x, 0.f);
  float a1v = fmaxf((t1-mu)*inv*gg.y + be.y, 0.f);
  unsigned pk = ((unsigned)f2bf_bits(a1v) << 16) | f2bf_bits(a0);
  *reinterpret_cast<unsigned*>(a1 + (size_t)p*128 + j) = pk;
}

// ---------------- MFMA bf16 GEMM: C[M][Nc] = A@B (+bias/prep) ----------------
// A row-major bf16 [M][lda].  B TRANSPOSED bf16: BT rows are output cols, row stride ldb,
// k-slice starts at column kofs (so BT[n*ldb + kofs + k]).
// EPI 0: bf16 store + atomicMax(maxbuf) with bias
// EPI 1: bf16 store with bias
// EPI 2: atomicMax only with bias
// EPI 3: f32 store (Cf) with bias
// EPI 4: bf16 store; per-row bias = prepg[(b*G+labels[m])*512 + n]
// 128x128 tile, BK=32, 256 threads (4 waves, each one 64x64 quadrant of 4x4 16x16 frags).
template<int EPI>
__global__ __launch_bounds__(256)
void mgemm(const u16* __restrict__ A, int lda, int K,
           const u16* __restrict__ BT, int ldb, int kofs,
           const float* __restrict__ bias, const float* __restrict__ prepg,
           const int* __restrict__ labels,
           u16* __restrict__ Cst, float* __restrict__ Cf, int ldc, int Nc,
           unsigned* __restrict__ maxbuf)
{
  __shared__ alignas(16) u16 As[128*32];
  __shared__ alignas(16) u16 Bs[128*32];
  int NBk = Nc >> 7;
  int bm = blockIdx.x / NBk, bn = blockIdx.x % NBk;
  int m0 = bm << 7, n0 = bn << 7;
  int tid = threadIdx.x;
  int lane = tid & 63, w = tid >> 6;
  int wr = w >> 1, wc = w & 1;
  int l15 = lane & 15, l4 = lane >> 4;
  // staging geometry: instr j in {0,1}: idx = j*256 + tid; row = idx>>2, kseg = (idx&3)*8
  int r0 = tid >> 2;             // row for j=0 (j=1 adds 64)
  int ks = (tid & 3) << 3;       // k element offset within tile
  // wave-uniform LDS dest bases (16B per lane appended by HW)
  u16* asd0 = As + (size_t)(w*64)*8;
  u16* asd1 = As + (size_t)(256 + w*64)*8;
  u16* bsd0 = Bs + (size_t)(w*64)*8;
  u16* bsd1 = Bs + (size_t)(256 + w*64)*8;
  f32x4 acc[4][4];
  #pragma unroll
  for (int i = 0; i < 4; ++i)
    #pragma unroll
    for (int jj = 0; jj < 4; ++jj)
      #pragma unroll
      for (int e = 0; e < 4; ++e) acc[i][jj][e] = 0.f;

  for (int k0 = 0; k0 < K; k0 += 32){
    // stage A tile [128][32]
    gload16(A + (size_t)(m0 + r0)*lda + k0 + ks, asd0);
    gload16(A + (size_t)(m0 + r0 + 64)*lda + k0 + ks, asd1);
    // stage B^T tile [128][32]
    gload16(BT + (size_t)(n0 + r0)*ldb + kofs + k0 + ks, bsd0);
    gload16(BT + (size_t)(n0 + r0 + 64)*ldb + kofs + k0 + ks, bsd1);
    __syncthreads();   // drains vmcnt(0): tiles complete
    bf16x8 af[4], bfr[4];
    #pragma unroll
    for (int i = 0; i < 4; ++i){
      af[i]  = *(const bf16x8*)&As[(size_t)(wr*64 + i*16 + l15)*32 + l4*8];
      bfr[i] = *(const bf16x8*)&Bs[(size_t)(wc*64 + i*16 + l15)*32 + l4*8];
    }
    #pragma unroll
    for (int i = 0; i < 4; ++i)
      #pragma unroll
      for (int jj = 0; jj < 4; ++jj)
        acc[i][jj] = __builtin_amdgcn_mfma_f32_16x16x32_bf16(af[i], bfr[jj], acc[i][jj], 0, 0, 0);
    __syncthreads();   // all reads done before next stage
  }

  // epilogue: D element (lane,reg): row = m0+wr*64+i*16+4*l4+reg, col = n0+wc*64+jj*16+l15
  float bi[4] = {0.f, 0.f, 0.f, 0.f};
  if (EPI != 4){
    #pragma unroll
    for (int jj = 0; jj < 4; ++jj) bi[jj] = bias[n0 + wc*64 + jj*16 + l15];
  }
  #pragma unroll
  for (int i = 0; i < 4; ++i){
    #pragma unroll
    for (int r = 0; r < 4; ++r){
      int m = m0 + wr*64 + i*16 + l4*4 + r;
      size_t grp = 0;
      if (EPI == 0 || EPI == 2 || EPI == 4)
        grp = (size_t)(m/NPTS)*NG + labels[m];
      #pragma unroll
      for (int jj = 0; jj < 4; ++jj){
        int n = n0 + wc*64 + jj*16 + l15;
        float v = acc[i][jj][r];
        if (EPI == 4) v += prepg[grp*512 + n];
        else          v += bi[jj];
        if (EPI == 0 || EPI == 1 || EPI == 4) Cst[(size_t)m*ldc + n] = f2bf_bits(v);
        if (EPI == 3) Cf[(size_t)m*ldc + n] = v;
        if (EPI == 0 || EPI == 2) atomicMax(maxbuf + (grp << 8) + n, mapf(v));
      }
    }
  }
}

// ---------------- pooled finalize: unmap, -inf -> 0, to bf16 ----------------
__global__ void k_poolfin(const unsigned* __restrict__ pu, u16* __restrict__ pbf){
  int i = blockIdx.x*blockDim.x + threadIdx.x;
  if (i >= NB_*NG*256) return;
  float v = unmapf(pu[i]);
  pbf[i] = f2bf_bits((v > -3.0e38f) ? v : 0.f);
}

// ---------------- LN2+ReLU in-place on u [P][512] bf16; wave per row ----------------
__global__ __launch_bounds__(256) void k_ln2(u16* __restrict__ u,
                                             const float* __restrict__ g2,
                                             const float* __restrict__ beta2){
  int row = (int)((blockIdx.x*blockDim.x + threadIdx.x) >> 6);
  int lane = threadIdx.x & 63;
  if (row >= NP) return;
  u16* r = u + (size_t)row*512;
  int c0 = lane*8;
  ushort4 lo = *(const ushort4*)(r + c0);
  ushort4 hi = *(const ushort4*)(r + c0 + 4);
  float v[8];
  v[0]=bf_bits2f(lo.x); v[1]=bf_bits2f(lo.y); v[2]=bf_bits2f(lo.z); v[3]=bf_bits2f(lo.w);
  v[4]=bf_bits2f(hi.x); v[5]=bf_bits2f(hi.y); v[6]=bf_bits2f(hi.z); v[7]=bf_bits2f(hi.w);
  float s = 0.f, sq = 0.f;
  #pragma unroll
  for (int k = 0; k < 8; ++k){ s += v[k]; sq += v[k]*v[k]; }
  #pragma unroll
  for (int m = 32; m; m >>= 1){ s += __shfl_xor(s, m); sq += __shfl_xor(sq, m); }
  float mu  = s * (1.f/512.f);
  float var = sq * (1.f/512.f) - mu*mu;
  float inv = rsqrtf(var + 1e-5f);
  float4 gA = *(const float4*)(g2 + c0), gB = *(const float4*)(g2 + c0 + 4);
  float4 bA = *(const float4*)(beta2 + c0), bB = *(const float4*)(beta2 + c0 + 4);
  float gg[8] = {gA.x,gA.y,gA.z,gA.w,gB.x,gB.y,gB.z,gB.w};
  float bb[8] = {bA.x,bA.y,bA.z,bA.w,bB.x,bB.y,bB.z,bB.w};
  ushort4 so, so2;
  u16 o[8];
  #pragma unroll
  for (int k = 0; k < 8; ++k)
    o[k] = f2bf_bits(fmaxf((v[k]-mu)*inv*gg[k] + bb[k], 0.f));
  so.x=o[0]; so.y=o[1]; so.z=o[2]; so.w=o[3];
  so2.x=o[4]; so2.y=o[5]; so2.z=o[6]; so2.w=o[7];
  *(ushort4*)(r + c0) = so;
  *(ushort4*)(r + c0 + 4) = so2;
}

// ---------------- out finalize ----------------
__global__ void k_outfin(const unsigned* __restrict__ ou, float* __restrict__ dst){
  int i = blockIdx.x*blockDim.x + threadIdx.x;
  if (i >= NB_*NG*256) return;
  float v = unmapf(ou[i]);
  dst[i] = (v > -3.0e38f) ? v : 0.f;
}

// ---------------- ws-too-small signal ----------------
__global__ void k_sig(float* __restrict__ out, float val){
  int i = blockIdx.x*blockDim.x + threadIdx.x;
  if (i < 256) out[i] = val;
}

extern "C" void kernel_launch(void* const* d_in, const int* in_sizes, int n_in,
                              void* d_out, int out_size, void* d_ws, size_t ws_size,
                              hipStream_t stream) {
  const float* xyz    = (const float*)d_in[0];
  const int*   labels = (const int*)  d_in[1];
  const float* w1a    = (const float*)d_in[2];
  const float* b1a    = (const float*)d_in[3];
  const float* g1     = (const float*)d_in[4];
  const float* beta1  = (const float*)d_in[5];
  const float* w1b    = (const float*)d_in[6];
  const float* b1b    = (const float*)d_in[7];
  const float* w2a    = (const float*)d_in[8];
  const float* b2a    = (const float*)d_in[9];
  const float* g2     = (const float*)d_in[10];
  const float* beta2  = (const float*)d_in[11];
  const float* w2b    = (const float*)d_in[12];
  const float* b2b    = (const float*)d_in[13];
  float* out = (float*)d_out;
  char* ws = (char*)d_ws;

  if (ws_size < WS_NEED){
    k_sig<<<1, 256, 0, stream>>>(out, 10000.f + (float)(ws_size >> 20));
    return;
  }

  float*     sums   = (float*)(ws + WS_SUMS);
  u16*       a1     = (u16*)(ws + WS_A1);
  u16*       h      = (u16*)(ws + WS_H);
  u16*       u      = (u16*)(ws + WS_U);
  unsigned*  pool_u = (unsigned*)(ws + WS_POOLU);
  u16*       poolbf = (u16*)(ws + WS_PBF);
  unsigned*  out_u  = (unsigned*)(ws + WS_OUTU);
  u16*       wt1    = (u16*)(ws + WS_WT1);
  u16*       wt2a   = (u16*)(ws + WS_WT2A);
  u16*       wt2b   = (u16*)(ws + WS_WT2B);
  float*     prepf  = (float*)(ws + WS_PREP);

  float* cent_out = out + OFF_CENT;
  float* out_seg  = out + OFF_OUT;
  float* pi_out   = out + OFF_PI;
  float* lab_out  = out + OFF_LAB;

  k_init<<<4096, 256, 0, stream>>>(sums, pool_u, out_u);
  // weight conversions (tiny)
  k_wt<<<(128*256+255)/256, 256, 0, stream>>>(w1b, wt1, 128, 256);
  k_wt<<<(512*512+255)/256, 256, 0, stream>>>(w2a, wt2a, 512, 512);
  k_wt<<<(512*256+255)/256, 256, 0, stream>>>(w2b, wt2b, 512, 256);
  k_points<<<NP/256, 256, 0, stream>>>(xyz, labels, sums, lab_out);
  k_cent<<<(NB_*NG+255)/256, 256, 0, stream>>>(sums, cent_out);
  k_mlp1<<<NP/4, 256, 0, stream>>>(xyz, labels, cent_out, w1a, b1a, g1, beta1, a1, pi_out);
  // GEMM1: h = a1 @ w1b + b1b ; store bf16 + pool atomicMax.  M=NP,K=128,N=256
  mgemm<0><<<(NP/128)*(256/128), 256, 0, stream>>>(
      a1, 128, 128, wt1, 128, 0, b1b, (const float*)nullptr, labels,
      h, (float*)nullptr, 256, 256, pool_u);
  k_poolfin<<<4096, 256, 0, stream>>>(pool_u, poolbf);
  // prep = poolbf @ w2a[0:256,:] + b2a : [B*G, 512] f32.  M=4096,K=256,N=512
  mgemm<3><<<(NB_*NG/128)*(512/128), 256, 0, stream>>>(
      poolbf, 256, 256, wt2a, 512, 0, b2a, (const float*)nullptr, labels,
      (u16*)nullptr, prepf, 512, 512, (unsigned*)nullptr);
  // GEMM2a': u = h @ w2a[256:512,:] + prep[gather] ; store bf16.  M=NP,K=256,N=512
  mgemm<4><<<(NP/128)*(512/128), 256, 0, stream>>>(
      h, 256, 256, wt2a, 512, 256, (const float*)nullptr, prepf, labels,
      u, (float*)nullptr, 512, 512, (unsigned*)nullptr);
  k_ln2<<<NP/4, 256, 0, stream>>>(u, g2, beta2);
  // GEMM2b: v = u @ w2b + b2b ; atomicMax only.  M=NP,K=512,N=256
  mgemm<2><<<(NP/128)*(256/128), 256, 0, stream>>>(
      u, 512, 512, wt2b, 512, 0, b2b, (const float*)nullptr, labels,
      (u16*)nullptr, (float*)nullptr, 0, 256, out_u);
  k_outfin<<<4096, 256, 0, stream>>>(out_u, out_seg);
}

// Round 5
// 427.357 us; speedup vs baseline: 4.0742x; 1.0097x over previous
//
#include <hip/hip_runtime.h>
#include <hip/hip_bf16.h>

// Problem constants
#define NB_  16
#define NPTS 8192
#define NG   256
#define NP   (NB_*NPTS)   // 131072 points

// Output segment offsets (floats)
#define OFF_CENT 0
#define OFF_OUT  12288
#define OFF_PI   1060864
#define OFF_LAB  1454080

typedef unsigned short u16;
typedef __attribute__((ext_vector_type(8))) short bf16x8;
typedef __attribute__((ext_vector_type(4))) float f32x4;

// Workspace layout (bytes)
static constexpr size_t WS_SUMS  = 0;                                // B*G*4 f32 = 64KB
static constexpr size_t WS_A1    = 65536;                            // P*128 bf16 = 32MB
static constexpr size_t WS_H     = WS_A1   + (size_t)NP*128*2;       // P*256 bf16 = 64MB
static constexpr size_t WS_POOLU = WS_H    + (size_t)NP*256*2;       // B*G*256 u32 = 4MB
static constexpr size_t WS_PBF   = WS_POOLU + (size_t)NB_*NG*256*4;  // B*G*256 bf16 = 2MB
static constexpr size_t WS_OUTU  = WS_PBF   + (size_t)NB_*NG*256*2;  // B*G*256 u32 = 4MB
static constexpr size_t WS_WT1   = WS_OUTU  + (size_t)NB_*NG*256*4;  // 256x128 bf16
static constexpr size_t WS_WT2A  = WS_WT1   + (size_t)256*128*2;     // 512x512 bf16
static constexpr size_t WS_WT2B  = WS_WT2A  + (size_t)512*512*2;     // 256x512 bf16
static constexpr size_t WS_PREP  = WS_WT2B  + (size_t)256*512*2;     // 4096x512 f32 = 8MB
static constexpr size_t WS_NEED  = WS_PREP  + (size_t)NB_*NG*512*4;  // ~115 MB

// Order-preserving float<->uint mapping for atomicMax-based segment max
__device__ __forceinline__ unsigned mapf(float x){
  unsigned u = __float_as_uint(x);
  return (u & 0x80000000u) ? ~u : (u | 0x80000000u);
}
__device__ __forceinline__ float unmapf(unsigned u){
  return (u & 0x80000000u) ? __uint_as_float(u & 0x7FFFFFFFu) : __uint_as_float(~u);
}
#define MAP_NEG_INF 0x007FFFFFu   // mapf(-inf)

__device__ __forceinline__ u16 f2bf_bits(float f){
  __hip_bfloat16 h = __float2bfloat16(f);
  union { __hip_bfloat16 h; u16 s; } u; u.h = h; return u.s;
}
__device__ __forceinline__ float bf_bits2f(u16 s){
  return __uint_as_float(((unsigned)s) << 16);
}

// async global->LDS, 16B per lane. LDS dest must be wave-uniform base (lane*16 added by HW).
__device__ __forceinline__ void gload16(const void* g, void* l){
  __builtin_amdgcn_global_load_lds((const __attribute__((address_space(1))) void*)g,
                                   (__attribute__((address_space(3))) void*)l, 16, 0, 0);
}

// ---------------- init: zero sums, -inf the max buffers ----------------
__global__ void k_init(float* __restrict__ sums, unsigned* __restrict__ pool_u,
                       unsigned* __restrict__ out_u){
  int i = blockIdx.x*blockDim.x + threadIdx.x;
  if (i < NB_*NG*4) sums[i] = 0.f;
  if (i < NB_*NG*256){ pool_u[i] = MAP_NEG_INF; out_u[i] = MAP_NEG_INF; }
}

// ---------------- weight transpose+bf16: dst[n*K+k] = bf16(src[k*N+n]) ----------------
__global__ void k_wt(const float* __restrict__ src, u16* __restrict__ dst, int K, int N){
  int i = blockIdx.x*blockDim.x + threadIdx.x;
  if (i >= K*N) return;
  int n = i / K, k = i - n*K;
  dst[i] = f2bf_bits(src[(size_t)k*N + n]);
}

// ---------------- per-point pass 1: segment sums + labels-as-float ----------------
__global__ void k_points(const float* __restrict__ xyz, const int* __restrict__ labels,
                         float* __restrict__ sums, float* __restrict__ outLab){
  int p = blockIdx.x*blockDim.x + threadIdx.x;
  if (p >= NP) return;
  int b = p / NPTS;
  int g = labels[p];
  float x = xyz[p*3+0], y = xyz[p*3+1], z = xyz[p*3+2];
  float* s = sums + (size_t)(b*NG + g)*4;
  atomicAdd(s+0, x); atomicAdd(s+1, y); atomicAdd(s+2, z); atomicAdd(s+3, 1.f);
  outLab[p] = (float)g;
}

// ---------------- centroids ----------------
__global__ void k_cent(const float* __restrict__ sums, float* __restrict__ cent_out){
  int i = blockIdx.x*blockDim.x + threadIdx.x;   // b*G+g
  if (i >= NB_*NG) return;
  const float* s = sums + (size_t)i*4;
  float c = fmaxf(s[3], 1.f);
  cent_out[i*3+0] = s[0]/c;
  cent_out[i*3+1] = s[1]/c;
  cent_out[i*3+2] = s[2]/c;
}

// ---------------- MLP1 front: rel@w1a+b1a -> LN -> ReLU -> a1 (bf16), also p_i ----------------
__global__ __launch_bounds__(256) void k_mlp1(
    const float* __restrict__ xyz, const int* __restrict__ labels,
    const float* __restrict__ cent,
    const float* __restrict__ w1a, const float* __restrict__ b1a,
    const float* __restrict__ g1, const float* __restrict__ beta1,
    u16* __restrict__ a1, float* __restrict__ pi_out)
{
  int wave = (int)((blockIdx.x*blockDim.x + threadIdx.x) >> 6);
  int lane = threadIdx.x & 63;
  int p = wave;
  if (p >= NP) return;
  int b = p / NPTS;
  int g = labels[p];
  const float* cb = cent + (size_t)(b*NG+g)*3;
  float c0 = cb[0], c1 = cb[1], c2 = cb[2];
  float r0 = xyz[p*3+0]-c0, r1 = xyz[p*3+1]-c1, r2 = xyz[p*3+2]-c2;
  if (lane < 3) pi_out[(size_t)p*3+lane] = (lane==0?c0:(lane==1?c1:c2));
  int j = lane*2;
  float2 wa0 = *(const float2*)(w1a + 0*128 + j);
  float2 wa1 = *(const float2*)(w1a + 1*128 + j);
  float2 wa2 = *(const float2*)(w1a + 2*128 + j);
  float2 bb  = *(const float2*)(b1a + j);
  float t0 = bb.x + r0*wa0.x + r1*wa1.x + r2*wa2.x;
  float t1 = bb.y + r0*wa0.y + r1*wa1.y + r2*wa2.y;
  float s = t0+t1, sq = t0*t0 + t1*t1;
  #pragma unroll
  for (int m = 32; m; m >>= 1){ s += __shfl_xor(s, m); sq += __shfl_xor(sq, m); }
  float mu  = s * (1.f/128.f);
  float var = sq * (1.f/128.f) - mu*mu;
  float inv = rsqrtf(var + 1e-5f);
  float2 gg = *(const float2*)(g1 + j), be = *(const float2*)(beta1 + j);
  float a0 = fmaxf((t0-mu)*inv*gg.x + be.x, 0.f);
  float a1v = fmaxf((t1-mu)*inv*gg.y + be.y, 0.f);
  unsigned pk = ((unsigned)f2bf_bits(a1v) << 16) | f2bf_bits(a0);
  *reinterpret_cast<unsigned*>(a1 + (size_t)p*128 + j) = pk;
}

// ---------------- MFMA bf16 GEMM (generic): C[M][Nc] = A@B + bias ----------------
// EPI 0: bf16 store + atomicMax(maxbuf);  EPI 3: f32 store (Cf).
template<int EPI>
__global__ __launch_bounds__(256)
void mgemm(const u16* __restrict__ A, int lda, int K,
           const u16* __restrict__ BT, int ldb, int kofs,
           const float* __restrict__ bias,
           const int* __restrict__ labels,
           u16* __restrict__ Cst, float* __restrict__ Cf, int ldc, int Nc,
           unsigned* __restrict__ maxbuf)
{
  __shared__ alignas(16) u16 As[128*32];
  __shared__ alignas(16) u16 Bs[128*32];
  int NBk = Nc >> 7;
  int bm = blockIdx.x / NBk, bn = blockIdx.x % NBk;
  int m0 = bm << 7, n0 = bn << 7;
  int tid = threadIdx.x;
  int lane = tid & 63, w = tid >> 6;
  int wr = w >> 1, wc = w & 1;
  int l15 = lane & 15, l4 = lane >> 4;
  int r0 = tid >> 2;
  int ks = (tid & 3) << 3;
  u16* asd0 = As + (size_t)(w*64)*8;
  u16* asd1 = As + (size_t)(256 + w*64)*8;
  u16* bsd0 = Bs + (size_t)(w*64)*8;
  u16* bsd1 = Bs + (size_t)(256 + w*64)*8;
  f32x4 acc[4][4];
  #pragma unroll
  for (int i = 0; i < 4; ++i)
    #pragma unroll
    for (int jj = 0; jj < 4; ++jj)
      #pragma unroll
      for (int e = 0; e < 4; ++e) acc[i][jj][e] = 0.f;

  for (int k0 = 0; k0 < K; k0 += 32){
    gload16(A + (size_t)(m0 + r0)*lda + k0 + ks, asd0);
    gload16(A + (size_t)(m0 + r0 + 64)*lda + k0 + ks, asd1);
    gload16(BT + (size_t)(n0 + r0)*ldb + kofs + k0 + ks, bsd0);
    gload16(BT + (size_t)(n0 + r0 + 64)*ldb + kofs + k0 + ks, bsd1);
    __syncthreads();
    bf16x8 af[4], bfr[4];
    #pragma unroll
    for (int i = 0; i < 4; ++i){
      af[i]  = *(const bf16x8*)&As[(size_t)(wr*64 + i*16 + l15)*32 + l4*8];
      bfr[i] = *(const bf16x8*)&Bs[(size_t)(wc*64 + i*16 + l15)*32 + l4*8];
    }
    #pragma unroll
    for (int i = 0; i < 4; ++i)
      #pragma unroll
      for (int jj = 0; jj < 4; ++jj)
        acc[i][jj] = __builtin_amdgcn_mfma_f32_16x16x32_bf16(af[i], bfr[jj], acc[i][jj], 0, 0, 0);
    __syncthreads();
  }

  float bi[4];
  #pragma unroll
  for (int jj = 0; jj < 4; ++jj) bi[jj] = bias[n0 + wc*64 + jj*16 + l15];
  #pragma unroll
  for (int i = 0; i < 4; ++i){
    #pragma unroll
    for (int r = 0; r < 4; ++r){
      int m = m0 + wr*64 + i*16 + l4*4 + r;
      size_t grp = 0;
      if (EPI == 0) grp = (size_t)(m/NPTS)*NG + labels[m];
      #pragma unroll
      for (int jj = 0; jj < 4; ++jj){
        int n = n0 + wc*64 + jj*16 + l15;
        float v = acc[i][jj][r] + bi[jj];
        if (EPI == 0){
          Cst[(size_t)m*ldc + n] = f2bf_bits(v);
          atomicMax(maxbuf + (grp << 8) + n, mapf(v));
        }
        if (EPI == 3) Cf[(size_t)m*ldc + n] = v;
      }
    }
  }
}

// ---------------- pooled finalize: unmap, -inf -> 0, to bf16 ----------------
__global__ void k_poolfin(const unsigned* __restrict__ pu, u16* __restrict__ pbf){
  int i = blockIdx.x*blockDim.x + threadIdx.x;
  if (i >= NB_*NG*256) return;
  float v = unmapf(pu[i]);
  pbf[i] = f2bf_bits((v > -3.0e38f) ? v : 0.f);
}

// ---------------- fused: u = h@W2a_bot + prep[gather] ; LN+ReLU ; v = u@w2b ; segmax ----
// 512 threads = 8 waves; M-tile 64 (grid NP/64); LDS 80KB -> 2 blocks/CU.
// Phase-1: K=256, waves 1x8 over N=512 (wave cols w*64..+63), acc[4][4].
// u kept in LDS [64][512] bf16, XOR-swizzled (byte ^= (row&7)<<4).
// Phase-2: K=512 from u_lds, N=256 (wave cols w*32..+31), acc2[4][2] -> atomicMax.
__global__ __launch_bounds__(512, 4)
void fused2(const u16* __restrict__ h, const u16* __restrict__ wt2a,
            const u16* __restrict__ wt2b, const float* __restrict__ prepf,
            const float* __restrict__ b2b, const float* __restrict__ g2,
            const float* __restrict__ beta2, const int* __restrict__ labels,
            unsigned* __restrict__ out_u)
{
  __shared__ alignas(16) char smem[81920];
  float* ssum = (float*)(smem + 65536);        // [64] f32 (aliases phase-2 B tile)
  float* ssq  = (float*)(smem + 65536 + 256);  // [64] f32
  int tid = threadIdx.x;
  int w = tid >> 6, lane = tid & 63;
  int l15 = lane & 15, l4 = lane >> 4;
  int m0 = blockIdx.x << 6;
  int srow = lane >> 2, skseg = (lane & 3) << 3;
  if (tid < 64){ ssum[tid] = 0.f; ssq[tid] = 0.f; }

  f32x4 acc[4][4];
  #pragma unroll
  for (int i = 0; i < 4; ++i)
    #pragma unroll
    for (int j = 0; j < 4; ++j)
      #pragma unroll
      for (int e = 0; e < 4; ++e) acc[i][j][e] = 0.f;

  // ---- phase 1: acc = h_tile @ W2a_bot ----
  for (int k0 = 0; k0 < 256; k0 += 32){
    if (w < 4)
      gload16(h + (size_t)(m0 + (w<<4) + srow)*256 + k0 + skseg, smem + (w<<10));
    #pragma unroll
    for (int q = 0; q < 4; ++q){
      int n = (w<<6) + (q<<4) + srow;
      gload16(wt2a + (size_t)n*512 + 256 + k0 + skseg,
              smem + 4096 + (((w<<6) + (q<<4)) << 6));
    }
    __syncthreads();
    bf16x8 af[4], bf[4];
    #pragma unroll
    for (int i = 0; i < 4; ++i)
      af[i] = *(const bf16x8*)(smem + ((((i<<4)+l15)) << 6) + (l4<<4));
    #pragma unroll
    for (int j = 0; j < 4; ++j)
      bf[j] = *(const bf16x8*)(smem + 4096 + (((w<<6)+(j<<4)+l15) << 6) + (l4<<4));
    #pragma unroll
    for (int i = 0; i < 4; ++i)
      #pragma unroll
      for (int j = 0; j < 4; ++j)
        acc[i][j] = __builtin_amdgcn_mfma_f32_16x16x32_bf16(af[i], bf[j], acc[i][j], 0, 0, 0);
    __syncthreads();
  }

  // ---- phase 1.5: + prep gather, LayerNorm + ReLU, write u to LDS (swizzled bf16) ----
  int gb = (m0 / NPTS) * NG;
  int grp[4][4];
  #pragma unroll
  for (int i = 0; i < 4; ++i)
    #pragma unroll
    for (int r = 0; r < 4; ++r)
      grp[i][r] = gb + labels[m0 + (i<<4) + (l4<<2) + r];
  #pragma unroll
  for (int i = 0; i < 4; ++i)
    #pragma unroll
    for (int j = 0; j < 4; ++j){
      int n = (w<<6) + (j<<4) + l15;
      #pragma unroll
      for (int r = 0; r < 4; ++r)
        acc[i][j][r] += prepf[((size_t)grp[i][r] << 9) + n];
    }
  #pragma unroll
  for (int i = 0; i < 4; ++i)
    #pragma unroll
    for (int r = 0; r < 4; ++r){
      float s = 0.f, q = 0.f;
      #pragma unroll
      for (int j = 0; j < 4; ++j){ float v = acc[i][j][r]; s += v; q += v*v; }
      #pragma unroll
      for (int mk = 1; mk < 16; mk <<= 1){ s += __shfl_xor(s, mk); q += __shfl_xor(q, mk); }
      if (l15 == 0){
        int row = (i<<4) + (l4<<2) + r;
        atomicAdd(&ssum[row], s);
        atomicAdd(&ssq[row], q);
      }
    }
  __syncthreads();
  if (tid < 64){
    float mu = ssum[tid] * (1.f/512.f);
    float var = ssq[tid] * (1.f/512.f) - mu*mu;
    ssum[tid] = mu;
    ssq[tid] = rsqrtf(var + 1e-5f);
  }
  __syncthreads();
  float gcol[4], bcol[4];
  #pragma unroll
  for (int j = 0; j < 4; ++j){
    int n = (w<<6) + (j<<4) + l15;
    gcol[j] = g2[n]; bcol[j] = beta2[n];
  }
  #pragma unroll
  for (int i = 0; i < 4; ++i)
    #pragma unroll
    for (int r = 0; r < 4; ++r){
      int row = (i<<4) + (l4<<2) + r;
      float mu = ssum[row], inv = ssq[row];
      #pragma unroll
      for (int j = 0; j < 4; ++j){
        int n = (w<<6) + (j<<4) + l15;
        float v = fmaxf((acc[i][j][r] - mu)*inv*gcol[j] + bcol[j], 0.f);
        int byo = (row << 10) + (n << 1);
        byo ^= (row & 7) << 4;
        *(u16*)(smem + byo) = f2bf_bits(v);
      }
    }
  __syncthreads();

  // ---- phase 2: v = u_lds @ w2b ; atomicMax segmax ----
  f32x4 acc2[4][2];
  #pragma unroll
  for (int i = 0; i < 4; ++i)
    #pragma unroll
    for (int j = 0; j < 2; ++j)
      #pragma unroll
      for (int e = 0; e < 4; ++e) acc2[i][j][e] = 0.f;

  for (int k0 = 0; k0 < 512; k0 += 32){
    #pragma unroll
    for (int q = 0; q < 2; ++q){
      int n = (w<<5) + (q<<4) + srow;
      gload16(wt2b + (size_t)n*512 + k0 + skseg,
              smem + 65536 + (((w<<5) + (q<<4)) << 6));
    }
    __syncthreads();
    bf16x8 af2[4], bf2[2];
    #pragma unroll
    for (int i = 0; i < 4; ++i){
      int row = (i<<4) + l15;
      int byo = (row << 10) + ((k0 + (l4<<3)) << 1);
      byo ^= (row & 7) << 4;
      af2[i] = *(const bf16x8*)(smem + byo);
    }
    #pragma unroll
    for (int j = 0; j < 2; ++j)
      bf2[j] = *(const bf16x8*)(smem + 65536 + (((w<<5)+(j<<4)+l15) << 6) + (l4<<4));
    #pragma unroll
    for (int i = 0; i < 4; ++i)
      #pragma unroll
      for (int j = 0; j < 2; ++j)
        acc2[i][j] = __builtin_amdgcn_mfma_f32_16x16x32_bf16(af2[i], bf2[j], acc2[i][j], 0, 0, 0);
    __syncthreads();
  }

  float bb0 = b2b[(w<<5) + l15], bb1 = b2b[(w<<5) + 16 + l15];
  #pragma unroll
  for (int i = 0; i < 4; ++i)
    #pragma unroll
    for (int r = 0; r < 4; ++r){
      unsigned gbase = ((unsigned)grp[i][r]) << 8;
      #pragma unroll
      for (int j = 0; j < 2; ++j){
        float v = acc2[i][j][r] + (j ? bb1 : bb0);
        atomicMax(out_u + gbase + (w<<5) + (j<<4) + l15, mapf(v));
      }
    }
}

// ---------------- out finalize ----------------
__global__ void k_outfin(const unsigned* __restrict__ ou, float* __restrict__ dst){
  int i = blockIdx.x*blockDim.x + threadIdx.x;
  if (i >= NB_*NG*256) return;
  float v = unmapf(ou[i]);
  dst[i] = (v > -3.0e38f) ? v : 0.f;
}

// ---------------- ws-too-small signal ----------------
__global__ void k_sig(float* __restrict__ out, float val){
  int i = blockIdx.x*blockDim.x + threadIdx.x;
  if (i < 256) out[i] = val;
}

extern "C" void kernel_launch(void* const* d_in, const int* in_sizes, int n_in,
                              void* d_out, int out_size, void* d_ws, size_t ws_size,
                              hipStream_t stream) {
  const float* xyz    = (const float*)d_in[0];
  const int*   labels = (const int*)  d_in[1];
  const float* w1a    = (const float*)d_in[2];
  const float* b1a    = (const float*)d_in[3];
  const float* g1     = (const float*)d_in[4];
  const float* beta1  = (const float*)d_in[5];
  const float* w1b    = (const float*)d_in[6];
  const float* b1b    = (const float*)d_in[7];
  const float* w2a    = (const float*)d_in[8];
  const float* b2a    = (const float*)d_in[9];
  const float* g2     = (const float*)d_in[10];
  const float* beta2  = (const float*)d_in[11];
  const float* w2b    = (const float*)d_in[12];
  const float* b2b    = (const float*)d_in[13];
  float* out = (float*)d_out;
  char* ws = (char*)d_ws;

  if (ws_size < WS_NEED){
    k_sig<<<1, 256, 0, stream>>>(out, 10000.f + (float)(ws_size >> 20));
    return;
  }

  float*     sums   = (float*)(ws + WS_SUMS);
  u16*       a1     = (u16*)(ws + WS_A1);
  u16*       h      = (u16*)(ws + WS_H);
  unsigned*  pool_u = (unsigned*)(ws + WS_POOLU);
  u16*       poolbf = (u16*)(ws + WS_PBF);
  unsigned*  out_u  = (unsigned*)(ws + WS_OUTU);
  u16*       wt1    = (u16*)(ws + WS_WT1);
  u16*       wt2a   = (u16*)(ws + WS_WT2A);
  u16*       wt2b   = (u16*)(ws + WS_WT2B);
  float*     prepf  = (float*)(ws + WS_PREP);

  float* cent_out = out + OFF_CENT;
  float* out_seg  = out + OFF_OUT;
  float* pi_out   = out + OFF_PI;
  float* lab_out  = out + OFF_LAB;

  k_init<<<4096, 256, 0, stream>>>(sums, pool_u, out_u);
  k_wt<<<(128*256+255)/256, 256, 0, stream>>>(w1b, wt1, 128, 256);
  k_wt<<<(512*512+255)/256, 256, 0, stream>>>(w2a, wt2a, 512, 512);
  k_wt<<<(512*256+255)/256, 256, 0, stream>>>(w2b, wt2b, 512, 256);
  k_points<<<NP/256, 256, 0, stream>>>(xyz, labels, sums, lab_out);
  k_cent<<<(NB_*NG+255)/256, 256, 0, stream>>>(sums, cent_out);
  k_mlp1<<<NP/4, 256, 0, stream>>>(xyz, labels, cent_out, w1a, b1a, g1, beta1, a1, pi_out);
  // GEMM1: h = a1 @ w1b + b1b ; bf16 store + pool atomicMax.  M=NP,K=128,N=256
  mgemm<0><<<(NP/128)*(256/128), 256, 0, stream>>>(
      a1, 128, 128, wt1, 128, 0, b1b, labels,
      h, (float*)nullptr, 256, 256, pool_u);
  k_poolfin<<<4096, 256, 0, stream>>>(pool_u, poolbf);
  // prep = poolbf @ w2a[0:256,:] + b2a : [B*G, 512] f32.  M=4096,K=256,N=512
  mgemm<3><<<(NB_*NG/128)*(512/128), 256, 0, stream>>>(
      poolbf, 256, 256, wt2a, 512, 0, b2a, labels,
      (u16*)nullptr, prepf, 512, 512, (unsigned*)nullptr);
  // fused: GEMM2a' + LN + GEMM2b + segmax
  fused2<<<NP/64, 512, 0, stream>>>(h, wt2a, wt2b, prepf, b2b, g2, beta2, labels, out_u);
  k_outfin<<<4096, 256, 0, stream>>>(out_u, out_seg);
}